// Round 4
// baseline (1953.544 us; speedup 1.0000x reference)
//
#include <hip/hip_runtime.h>

// Decoder_8014408974552 R8: R7 structure with the register cap fixed.
// R7 POST-MORTEM: __launch_bounds__(512,2) acted as min-2-BLOCKS/CU ->
// 4 waves/SIMD target -> VGPR cap 128 (pool 512/SIMD). The ~230-reg live
// set spilled wholesale: FETCH 36.6 MB -> 634 MB of scratch traffic at
// ~355 GB/s = the whole runtime. The pair-split structure itself was fine
// (Occupancy 24.2%, passed, absmax 0.125).
// R8: identical kernel, but __launch_bounds__(512) + amdgpu_waves_per_eu(2)
// -> VGPR cap 256, fits the live set, 2 waves/SIMD with no spill.

#define TT  30
#define NHP 50      // superphases per timestep
#define SPU 12288   // u16 per superphase (24576 B = 2 roles x 12 frags x 1KB)
#define RHU 6144    // u16 per role half (12 frags)
#define HS  392     // hn row stride in u16 (784 B, 16B-aligned, 0 conflicts)

typedef unsigned short u16;
typedef __bf16 bf16x8 __attribute__((ext_vector_type(8)));
typedef u16    u16x8  __attribute__((ext_vector_type(8)));
typedef float  f32x16 __attribute__((ext_vector_type(16)));

__device__ __forceinline__ u16 f2b(float f){           // fp32 -> bf16 RNE
  unsigned u = __float_as_uint(f);
  u += 0x7FFFu + ((u >> 16) & 1u);
  return (u16)(u >> 16);
}
__device__ __forceinline__ float b2f(u16 h){ return __uint_as_float(((unsigned)h) << 16); }

__device__ __forceinline__ f32x16 mfma32(u16x8 a, u16x8 b, f32x16 c){
  return __builtin_amdgcn_mfma_f32_32x32x16_bf16(
      __builtin_bit_cast(bf16x8, a), __builtin_bit_cast(bf16x8, b), c, 0, 0, 0);
}
__device__ __forceinline__ void lds_fence(){ asm volatile("s_waitcnt lgkmcnt(0)" ::: "memory"); }
__device__ __forceinline__ void vm_fence(){ asm volatile("s_waitcnt vmcnt(0)" ::: "memory"); }
__device__ __forceinline__ float sigf(float x){ return __builtin_amdgcn_rcpf(1.f + __expf(-x)); }
__device__ __forceinline__ float tanh_(float x){ return 2.f*__builtin_amdgcn_rcpf(1.f + __expf(-2.f*x)) - 1.f; }

__device__ __forceinline__ void stage16(const u16* g, u16* l){
  __builtin_amdgcn_global_load_lds(
      (const __attribute__((address_space(1))) unsigned int*)g,
      (__attribute__((address_space(3))) unsigned int*)l, 16, 0, 0);
}

// ---------------------------------------------------------------- prep ----
// Per-role frag sequence per t (600 frags), role r owns chunks r*6..r*6+5:
//   chunk ci (0..5): base=ci*96
//     gi : q = base + g*8 + kf        (g=0..2 gates r/z/n, kf=0..7,  24 frags)
//     ghX: q = base + 24 + g*24 + kf  (g=0..2, kf=0..23,             72 frags)
//   decode tile r:  q = 576 + kf      (kf=0..23)
// superphase sp=q/12, slot f=q%12; stream u16 offset =
//   sp*SPU + role*RHU + f*512 + (lc+32*hl)*8 + j
__global__ void prep_kernel(const float* __restrict__ Wih, const float* __restrict__ Whh,
                            const float* __restrict__ Wd1, const float* __restrict__ Wd2,
                            const float* __restrict__ bih, const float* __restrict__ bhh,
                            const float* __restrict__ Ws,  const float* __restrict__ bs,
                            const float* __restrict__ Wp,  const float* __restrict__ bp,
                            u16* __restrict__ stream, u16* __restrict__ wd2p,
                            u16* __restrict__ wxp, float* __restrict__ gb)
{
  int i = blockIdx.x*blockDim.x + threadIdx.x;
  if (i < 442368){  // W_hh [1152][384]
    int row = i/384, k = i - row*384;
    int g = row/384, unit = row - g*384, c = unit>>5, lc = unit&31;
    int kf = k>>4, hl = (k>>3)&1, j = k&7;
    int role = c/6, ci = c - role*6;
    int q = ci*96 + 24 + g*24 + kf;
    int sp = q/12, f = q - sp*12;
    stream[(size_t)sp*SPU + role*RHU + f*512 + (lc+32*hl)*8 + j] = f2b(Whh[i]);
  }
  if (i < 147456){  // W_ih [1152][128]
    int row = i>>7, k = i&127;
    int g = row/384, unit = row - g*384, c = unit>>5, lc = unit&31;
    int kf = k>>4, hl = (k>>3)&1, j = k&7;
    int role = c/6, ci = c - role*6;
    int q = ci*96 + g*8 + kf;
    int sp = q/12, f = q - sp*12;
    stream[(size_t)sp*SPU + role*RHU + f*512 + (lc+32*hl)*8 + j] = f2b(Wih[i]);
  }
  if (i < 24576){   // Wd1 [64][384]; tile ct -> role ct
    int row = i/384, k = i - row*384;
    int ct = row>>5, lc = row&31;
    int kf = k>>4, hl = (k>>3)&1, j = k&7;
    int q = 576 + kf;
    int sp = q/12, f = q - sp*12;
    stream[(size_t)sp*SPU + ct*RHU + f*512 + (lc+32*hl)*8 + j] = f2b(Wd1[i]);
  }
  if (i < 2048){    // Wd2 padded B-frags [4 kf][512] (n>=3 -> 0)
    int kf = i>>9, r = i&511;
    int n = (r>>3)&31, hl = r>>8, j = r&7;
    int k = kf*16 + hl*8 + j;
    wd2p[i] = f2b((n<3) ? Wd2[n*64 + k] : 0.f);
  }
  if (i < 2048){    // x-MLP B-frags [4 tiles][512]: K=16 (k=0..7 feat, 8..15 zero)
    int tl = i>>9, r = i&511;
    int n = (r>>3)&31, hl = r>>8, j = r&7;
    int k = hl*8 + j, u = tl*32 + n;
    float v = 0.f;
    if      (k <= 2) v = Ws[u*3 + k];
    else if (k == 3) v = bs[u];
    else if (k <= 6) v = Wp[u*3 + (k-4)];
    else if (k == 7) v = bp[u];
    wxp[i] = f2b(v);
  }
  if (i < 384){     // fused gate biases per hidden unit: {r, z, n_i, n_h}
    gb[i*4+0] = bih[i]       + bhh[i];
    gb[i*4+1] = bih[384+i]   + bhh[384+i];
    gb[i*4+2] = bih[768+i];
    gb[i*4+3] = bhh[768+i];
  }
}

// ---------------------------------------------------------------- main ----
__global__ __launch_bounds__(512) __attribute__((amdgpu_waves_per_eu(2)))
void gru_main(const float* __restrict__ ih, const float* __restrict__ plan,
              const float* __restrict__ gate, const float* __restrict__ istate,
              const u16* __restrict__ stream, const u16* __restrict__ wd2p,
              const u16* __restrict__ wxp, const float* __restrict__ gb,
              const float* __restrict__ bd1, const float* __restrict__ bd2,
              float* __restrict__ out)
{
  __shared__ __attribute__((aligned(16))) u16 wb[2][SPU];   //  49152 B
  __shared__ __attribute__((aligned(16))) u16 hn[4][32*HS]; // 100352 B (pair-shared h)
  __shared__ float sst[4][32][4];                           //   2048 B
  // total 151552 B -> 1 block/CU, 8 waves = 2 waves/SIMD

  const int tid  = threadIdx.x;
  const int wave = tid >> 6, lane = tid & 63;
  const int pair = wave >> 1, role = wave & 1;
  const int m    = lane & 31, hl = lane >> 5;
  const int R0   = blockIdx.x*128 + pair*32;   // pair's 32 batch rows
  u16* hw = hn[pair];
  const int scol = role*192;                   // role's scratch col base

  const float gt   = gate[R0 + m];
  const float bd1v = bd1[role*32 + m];
  const float bd2v = (m<3) ? bd2[m] : 0.f;

  if (role==0 && lane < 32){
    const float* sp = istate + (size_t)(R0+lane)*3;
    sst[pair][lane][0]=sp[0]; sst[pair][lane][1]=sp[1];
    sst[pair][lane][2]=sp[2]; sst[pair][lane][3]=0.f;
  }

  // initial hidden -> A-frags (both roles); role 0 seeds the LDS h-buffer
  u16x8 hold[24];
#pragma unroll
  for (int kf=0; kf<24; ++kf){
    const float* p = ih + (size_t)(R0+m)*384 + kf*16 + hl*8;
    float4 a = *(const float4*)p;
    float4 b = *(const float4*)(p+4);
    u16x8 v;
    v[0]=f2b(a.x); v[1]=f2b(a.y); v[2]=f2b(a.z); v[3]=f2b(a.w);
    v[4]=f2b(b.x); v[5]=f2b(b.y); v[6]=f2b(b.z); v[7]=f2b(b.w);
    hold[kf]=v;
    if (role==0) *(u16x8*)&hw[m*HS + kf*16 + hl*8] = v;
  }

  const u16* srcb = stream + wave*1536 + lane*8;  // 8 waves x 1536 u16 stripes
  auto stage = [&](int sp, int bsel){
    const u16* s = srcb + (size_t)sp*SPU;
    u16* d = &wb[bsel][wave*1536];
#pragma unroll
    for (int ii=0; ii<3; ++ii) stage16(s + ii*512, d + ii*512);
  };

  stage(0, 0);
  vm_fence(); __syncthreads();
  int buf = 0, gp = 0;

#pragma unroll 1
  for (int t=0; t<TT; ++t){
    // ---- x = (state@Ws^T+bs) + gate*(plan@Wp^T+bp); both roles build full xf
    u16x8 a8;
    {
      float4 sv = *(const float4*)&sst[pair][m][0];
      const float* pp = plan + (size_t)(R0+m)*(TT*3) + t*3;
      float f0=sv.x, f1=sv.y, f2=sv.z, f3=1.f;
      float f4=gt*pp[0], f5=gt*pp[1], f6=gt*pp[2], f7=gt;
      if (hl){ a8[0]=0;a8[1]=0;a8[2]=0;a8[3]=0;a8[4]=0;a8[5]=0;a8[6]=0;a8[7]=0; }
      else { a8[0]=f2b(f0);a8[1]=f2b(f1);a8[2]=f2b(f2);a8[3]=f2b(f3);
             a8[4]=f2b(f4);a8[5]=f2b(f5);a8[6]=f2b(f6);a8[7]=f2b(f7); }
    }
    u16x8 xf[8];
#pragma unroll
    for (int tl=0; tl<4; ++tl){
      f32x16 ax;
#pragma unroll
      for (int r=0;r<16;++r) ax[r]=0.f;
      ax = mfma32(a8, *(const u16x8*)(wxp + tl*512 + lane*8), ax);
      // C-layout -> own scratch slice -> A-frags
#pragma unroll
      for (int r=0;r<16;++r){
        int row = (r&3) + ((r>>2)<<3) + 4*hl;
        hw[row*HS + scol + m] = f2b(ax[r]);
      }
      lds_fence();
      xf[2*tl]   = *(const u16x8*)&hw[m*HS + scol + hl*8];
      xf[2*tl+1] = *(const u16x8*)&hw[m*HS + scol + 16 + hl*8];
      lds_fence();
    }
    // restore own slice with old h (CONSTANT reg indices via role branch)
    if (role==0){
      *(u16x8*)&hw[m*HS + hl*8]       = hold[0];
      *(u16x8*)&hw[m*HS + 16 + hl*8]  = hold[1];
    } else {
      *(u16x8*)&hw[m*HS + 192 + hl*8] = hold[12];
      *(u16x8*)&hw[m*HS + 208 + hl*8] = hold[13];
    }
    lds_fence();

    // ---- 6 chunks x 8 superphases (role's chunks: role*6 + ci)
#pragma unroll 1
    for (int ci=0; ci<6; ++ci){
      const int colb = scol + ci*32;           // this chunk's h columns
      f32x16 aR, aZ, aNI, aNH;
      {
        const float4 b4 = *(const float4*)(gb + (size_t)(colb+m)*4);
#pragma unroll
        for (int r=0;r<16;++r){ aR[r]=b4.x; aZ[r]=b4.y; aNI[r]=b4.z; aNH[r]=b4.w; }
      }
      { // hp0: gi_r kf0..7 (f0..7), gi_z kf0..3 (f8..11)
        int np = gp+1; stage(np, buf^1);
        const u16* W = wb[buf] + role*RHU;
#pragma unroll
        for (int kf=0; kf<8; ++kf)
          aR = mfma32(xf[kf], *(const u16x8*)(W + kf*512 + lane*8), aR);
#pragma unroll
        for (int kf=0; kf<4; ++kf)
          aZ = mfma32(xf[kf], *(const u16x8*)(W + (8+kf)*512 + lane*8), aZ);
        vm_fence(); __syncthreads(); buf^=1; gp=np;
      }
      { // hp1: gi_z kf4..7 (f0..3), gi_n kf0..7 (f4..11)
        int np = gp+1; stage(np, buf^1);
        const u16* W = wb[buf] + role*RHU;
#pragma unroll
        for (int kf=4; kf<8; ++kf)
          aZ = mfma32(xf[kf], *(const u16x8*)(W + (kf-4)*512 + lane*8), aZ);
#pragma unroll
        for (int kf=0; kf<8; ++kf)
          aNI = mfma32(xf[kf], *(const u16x8*)(W + (4+kf)*512 + lane*8), aNI);
        vm_fence(); __syncthreads(); buf^=1; gp=np;
      }
      { // hp2: gh_r kf0..11
        int np = gp+1; stage(np, buf^1);
        const u16* W = wb[buf] + role*RHU;
#pragma unroll
        for (int kf=0; kf<12; ++kf)
          aR = mfma32(hold[kf], *(const u16x8*)(W + kf*512 + lane*8), aR);
        vm_fence(); __syncthreads(); buf^=1; gp=np;
      }
      { // hp3: gh_r kf12..23
        int np = gp+1; stage(np, buf^1);
        const u16* W = wb[buf] + role*RHU;
#pragma unroll
        for (int kk=0; kk<12; ++kk)
          aR = mfma32(hold[12+kk], *(const u16x8*)(W + kk*512 + lane*8), aR);
        vm_fence(); __syncthreads(); buf^=1; gp=np;
      }
      { // hp4: gh_z kf0..11
        int np = gp+1; stage(np, buf^1);
        const u16* W = wb[buf] + role*RHU;
#pragma unroll
        for (int kf=0; kf<12; ++kf)
          aZ = mfma32(hold[kf], *(const u16x8*)(W + kf*512 + lane*8), aZ);
        vm_fence(); __syncthreads(); buf^=1; gp=np;
      }
      { // hp5: gh_z kf12..23
        int np = gp+1; stage(np, buf^1);
        const u16* W = wb[buf] + role*RHU;
#pragma unroll
        for (int kk=0; kk<12; ++kk)
          aZ = mfma32(hold[12+kk], *(const u16x8*)(W + kk*512 + lane*8), aZ);
        vm_fence(); __syncthreads(); buf^=1; gp=np;
      }
      { // hp6: gh_n kf0..11
        int np = gp+1; stage(np, buf^1);
        const u16* W = wb[buf] + role*RHU;
#pragma unroll
        for (int kf=0; kf<12; ++kf)
          aNH = mfma32(hold[kf], *(const u16x8*)(W + kf*512 + lane*8), aNH);
        vm_fence(); __syncthreads(); buf^=1; gp=np;
      }
      { // hp7: gh_n kf12..23 + GRU elementwise blend in place
        int np = gp+1; stage(np, buf^1);
        const u16* W = wb[buf] + role*RHU;
#pragma unroll
        for (int kk=0; kk<12; ++kk)
          aNH = mfma32(hold[12+kk], *(const u16x8*)(W + kk*512 + lane*8), aNH);
#pragma unroll
        for (int r=0;r<16;++r){
          int row = (r&3) + ((r>>2)<<3) + 4*hl;
          float rr = sigf(aR[r]);
          float zz = sigf(aZ[r]);
          float nn = tanh_(aNI[r] + rr*aNH[r]);
          int off = row*HS + colb + m;
          float ho = b2f(hw[off]);             // old h
          hw[off] = f2b((1.f-zz)*nn + zz*ho);  // new h, in place
        }
        vm_fence(); __syncthreads(); buf^=1; gp=np;
      }
    } // chunks

    // ---- reload hold[] (full new h; all blends done before hp47's barrier)
#pragma unroll
    for (int kf=0; kf<24; ++kf)
      hold[kf] = *(const u16x8*)&hw[m*HS + kf*16 + hl*8];

    // ---- decode: this role's Wd1 tile over 2 superphases
    f32x16 a0;
#pragma unroll
    for (int r=0;r<16;++r) a0[r]=bd1v;
    { // hp48: Wd1 tile kf0..11
      int np = gp+1; stage(np, buf^1);
      const u16* W = wb[buf] + role*RHU;
#pragma unroll
      for (int kf=0; kf<12; ++kf)
        a0 = mfma32(hold[kf], *(const u16x8*)(W + kf*512 + lane*8), a0);
      vm_fence(); __syncthreads(); buf^=1; gp=np;
    }
    { // hp49: Wd1 tile kf12..23 + elu into own scratch slice; stage wraps
      int np = (gp+1 == NHP) ? 0 : gp+1;
      stage(np, buf^1);
      const u16* W = wb[buf] + role*RHU;
#pragma unroll
      for (int kk=0; kk<12; ++kk)
        a0 = mfma32(hold[12+kk], *(const u16x8*)(W + kk*512 + lane*8), a0);
#pragma unroll
      for (int r=0;r<16;++r){
        int row = (r&3) + ((r>>2)<<3) + 4*hl;
        float e = a0[r]; e = e>0.f ? e : (__expf(e)-1.f);
        hw[row*HS + scol + m] = f2b(e);
      }
      vm_fence(); __syncthreads(); buf^=1; gp=np;
    }
    // ---- epilogue: d2 from BOTH roles' elu slices
    {
      u16x8 wd2f0 = *(const u16x8*)(wd2p + 0*512 + lane*8);
      u16x8 wd2f1 = *(const u16x8*)(wd2p + 1*512 + lane*8);
      u16x8 wd2f2 = *(const u16x8*)(wd2p + 2*512 + lane*8);
      u16x8 wd2f3 = *(const u16x8*)(wd2p + 3*512 + lane*8);

      u16x8 af0 = *(const u16x8*)&hw[m*HS + hl*8];         // d1 units  0..15
      u16x8 af1 = *(const u16x8*)&hw[m*HS + 16  + hl*8];   //          16..31
      u16x8 af2 = *(const u16x8*)&hw[m*HS + 192 + hl*8];   //          32..47
      u16x8 af3 = *(const u16x8*)&hw[m*HS + 208 + hl*8];   //          48..63
      f32x16 ao;
#pragma unroll
      for (int r=0;r<16;++r) ao[r]=0.f;
      ao = mfma32(af0, wd2f0, ao);
      ao = mfma32(af1, wd2f1, ao);
      ao = mfma32(af2, wd2f2, ao);
      ao = mfma32(af3, wd2f3, ao);

      // all cross-slice reads done before anyone overwrites the slices
      __syncthreads();

      // restore own slice with NEW h (constant reg indices via role branch)
      if (role==0){
        *(u16x8*)&hw[m*HS + hl*8]       = hold[0];
        *(u16x8*)&hw[m*HS + 16 + hl*8]  = hold[1];
      } else {
        *(u16x8*)&hw[m*HS + 192 + hl*8] = hold[12];
        *(u16x8*)&hw[m*HS + 208 + hl*8] = hold[13];
      }

      // out + state update (role 0 writes; C cols 0..2 valid)
      if (role==0){
#pragma unroll
        for (int r=0;r<16;++r){
          int row = (r&3) + ((r>>2)<<3) + 4*hl;
          if (m < 3){
            float ns = sst[pair][row][m] + ao[r] + bd2v;
            out[(size_t)(R0+row)*(TT*3) + t*3 + m] = ns;
            sst[pair][row][m] = ns;
          }
        }
      }
      __syncthreads();   // sst + slice restores visible before next t
    }
  } // t
}

// -------------------------------------------------------------- launch ----
extern "C" void kernel_launch(void* const* d_in, const int* in_sizes, int n_in,
                              void* d_out, int out_size, void* d_ws, size_t ws_size,
                              hipStream_t stream)
{
  (void)in_sizes; (void)n_in; (void)out_size; (void)ws_size;
  const float* ih     = (const float*)d_in[0];
  const float* plan   = (const float*)d_in[1];
  const float* gatep  = (const float*)d_in[2];
  const float* istate = (const float*)d_in[3];
  const float* Wp     = (const float*)d_in[4];
  const float* bp     = (const float*)d_in[5];
  const float* Ws     = (const float*)d_in[6];
  const float* bs     = (const float*)d_in[7];
  const float* Wih    = (const float*)d_in[8];
  const float* bih    = (const float*)d_in[9];
  const float* Whh    = (const float*)d_in[10];
  const float* bhh    = (const float*)d_in[11];
  const float* Wd1    = (const float*)d_in[12];
  const float* bd1    = (const float*)d_in[13];
  const float* Wd2    = (const float*)d_in[14];
  const float* bd2    = (const float*)d_in[15];

  // workspace layout (~1.25 MB)
  u16*   wstream = (u16*)d_ws;                         // 614400 u16 = 1228800 B
  u16*   wd2p    = (u16*)((char*)d_ws + 1228800);      //   2048 u16 =    4096 B
  u16*   wxp     = (u16*)((char*)d_ws + 1232896);      //   2048 u16 =    4096 B
  float* gb      = (float*)((char*)d_ws + 1236992);    //   1536 f32 =    6144 B

  prep_kernel<<<1728, 256, 0, stream>>>(Wih, Whh, Wd1, Wd2, bih, bhh, Ws, bs, Wp, bp,
                                        wstream, wd2p, wxp, gb);
  gru_main<<<256, 512, 0, stream>>>(ih, plan, gatep, istate,
                                    wstream, wd2p, wxp, gb, bd1, bd2, (float*)d_out);
}

// Round 5
// 1952.225 us; speedup vs baseline: 1.0007x; 1.0007x over previous
//
#include <hip/hip_runtime.h>

// Decoder_8014408974552 R9: R7 structure, register cap ACTUALLY fixed.
// R7/R8 POST-MORTEM: on this toolchain __launch_bounds__'s 2nd arg behaves
// as min BLOCKS/CU (CUDA semantics): (256,1)->cap 512 (R4, used 244);
// (512,2)->2x8 waves/4EU = 4 waves/EU -> cap 128 -> wholesale spill
// (FETCH 36MB->631MB, the whole slowdown). amdgpu_waves_per_eu(2) next to
// the macro was ignored (R8 binary identical to R7).
// R9: __launch_bounds__(512, 1) -> 1 block x 8 waves / 4 EU = 2 waves/EU
// -> VGPR cap 256, fits the ~230-reg live set. Kernel body = R7 verbatim
// (passed twice, absmax 0.125): 4 pairs x 2 roles, role-split chunks,
// double-buffered 24KB superphases, 2 waves/SIMD to hide lgkm/vmcnt/barrier.

#define TT  30
#define NHP 50      // superphases per timestep
#define SPU 12288   // u16 per superphase (24576 B = 2 roles x 12 frags x 1KB)
#define RHU 6144    // u16 per role half (12 frags)
#define HS  392     // hn row stride in u16 (784 B, 16B-aligned, 0 conflicts)

typedef unsigned short u16;
typedef __bf16 bf16x8 __attribute__((ext_vector_type(8)));
typedef u16    u16x8  __attribute__((ext_vector_type(8)));
typedef float  f32x16 __attribute__((ext_vector_type(16)));

__device__ __forceinline__ u16 f2b(float f){           // fp32 -> bf16 RNE
  unsigned u = __float_as_uint(f);
  u += 0x7FFFu + ((u >> 16) & 1u);
  return (u16)(u >> 16);
}
__device__ __forceinline__ float b2f(u16 h){ return __uint_as_float(((unsigned)h) << 16); }

__device__ __forceinline__ f32x16 mfma32(u16x8 a, u16x8 b, f32x16 c){
  return __builtin_amdgcn_mfma_f32_32x32x16_bf16(
      __builtin_bit_cast(bf16x8, a), __builtin_bit_cast(bf16x8, b), c, 0, 0, 0);
}
__device__ __forceinline__ void lds_fence(){ asm volatile("s_waitcnt lgkmcnt(0)" ::: "memory"); }
__device__ __forceinline__ void vm_fence(){ asm volatile("s_waitcnt vmcnt(0)" ::: "memory"); }
__device__ __forceinline__ float sigf(float x){ return __builtin_amdgcn_rcpf(1.f + __expf(-x)); }
__device__ __forceinline__ float tanh_(float x){ return 2.f*__builtin_amdgcn_rcpf(1.f + __expf(-2.f*x)) - 1.f; }

__device__ __forceinline__ void stage16(const u16* g, u16* l){
  __builtin_amdgcn_global_load_lds(
      (const __attribute__((address_space(1))) unsigned int*)g,
      (__attribute__((address_space(3))) unsigned int*)l, 16, 0, 0);
}

// ---------------------------------------------------------------- prep ----
// Per-role frag sequence per t (600 frags), role r owns chunks r*6..r*6+5:
//   chunk ci (0..5): base=ci*96
//     gi : q = base + g*8 + kf        (g=0..2 gates r/z/n, kf=0..7,  24 frags)
//     ghX: q = base + 24 + g*24 + kf  (g=0..2, kf=0..23,             72 frags)
//   decode tile r:  q = 576 + kf      (kf=0..23)
// superphase sp=q/12, slot f=q%12; stream u16 offset =
//   sp*SPU + role*RHU + f*512 + (lc+32*hl)*8 + j
__global__ void prep_kernel(const float* __restrict__ Wih, const float* __restrict__ Whh,
                            const float* __restrict__ Wd1, const float* __restrict__ Wd2,
                            const float* __restrict__ bih, const float* __restrict__ bhh,
                            const float* __restrict__ Ws,  const float* __restrict__ bs,
                            const float* __restrict__ Wp,  const float* __restrict__ bp,
                            u16* __restrict__ stream, u16* __restrict__ wd2p,
                            u16* __restrict__ wxp, float* __restrict__ gb)
{
  int i = blockIdx.x*blockDim.x + threadIdx.x;
  if (i < 442368){  // W_hh [1152][384]
    int row = i/384, k = i - row*384;
    int g = row/384, unit = row - g*384, c = unit>>5, lc = unit&31;
    int kf = k>>4, hl = (k>>3)&1, j = k&7;
    int role = c/6, ci = c - role*6;
    int q = ci*96 + 24 + g*24 + kf;
    int sp = q/12, f = q - sp*12;
    stream[(size_t)sp*SPU + role*RHU + f*512 + (lc+32*hl)*8 + j] = f2b(Whh[i]);
  }
  if (i < 147456){  // W_ih [1152][128]
    int row = i>>7, k = i&127;
    int g = row/384, unit = row - g*384, c = unit>>5, lc = unit&31;
    int kf = k>>4, hl = (k>>3)&1, j = k&7;
    int role = c/6, ci = c - role*6;
    int q = ci*96 + g*8 + kf;
    int sp = q/12, f = q - sp*12;
    stream[(size_t)sp*SPU + role*RHU + f*512 + (lc+32*hl)*8 + j] = f2b(Wih[i]);
  }
  if (i < 24576){   // Wd1 [64][384]; tile ct -> role ct
    int row = i/384, k = i - row*384;
    int ct = row>>5, lc = row&31;
    int kf = k>>4, hl = (k>>3)&1, j = k&7;
    int q = 576 + kf;
    int sp = q/12, f = q - sp*12;
    stream[(size_t)sp*SPU + ct*RHU + f*512 + (lc+32*hl)*8 + j] = f2b(Wd1[i]);
  }
  if (i < 2048){    // Wd2 padded B-frags [4 kf][512] (n>=3 -> 0)
    int kf = i>>9, r = i&511;
    int n = (r>>3)&31, hl = r>>8, j = r&7;
    int k = kf*16 + hl*8 + j;
    wd2p[i] = f2b((n<3) ? Wd2[n*64 + k] : 0.f);
  }
  if (i < 2048){    // x-MLP B-frags [4 tiles][512]: K=16 (k=0..7 feat, 8..15 zero)
    int tl = i>>9, r = i&511;
    int n = (r>>3)&31, hl = r>>8, j = r&7;
    int k = hl*8 + j, u = tl*32 + n;
    float v = 0.f;
    if      (k <= 2) v = Ws[u*3 + k];
    else if (k == 3) v = bs[u];
    else if (k <= 6) v = Wp[u*3 + (k-4)];
    else if (k == 7) v = bp[u];
    wxp[i] = f2b(v);
  }
  if (i < 384){     // fused gate biases per hidden unit: {r, z, n_i, n_h}
    gb[i*4+0] = bih[i]       + bhh[i];
    gb[i*4+1] = bih[384+i]   + bhh[384+i];
    gb[i*4+2] = bih[768+i];
    gb[i*4+3] = bhh[768+i];
  }
}

// ---------------------------------------------------------------- main ----
__global__ __launch_bounds__(512, 1)
void gru_main(const float* __restrict__ ih, const float* __restrict__ plan,
              const float* __restrict__ gate, const float* __restrict__ istate,
              const u16* __restrict__ stream, const u16* __restrict__ wd2p,
              const u16* __restrict__ wxp, const float* __restrict__ gb,
              const float* __restrict__ bd1, const float* __restrict__ bd2,
              float* __restrict__ out)
{
  __shared__ __attribute__((aligned(16))) u16 wb[2][SPU];   //  49152 B
  __shared__ __attribute__((aligned(16))) u16 hn[4][32*HS]; // 100352 B (pair-shared h)
  __shared__ float sst[4][32][4];                           //   2048 B
  // total 151552 B -> 1 block/CU, 8 waves = 2 waves/SIMD

  const int tid  = threadIdx.x;
  const int wave = tid >> 6, lane = tid & 63;
  const int pair = wave >> 1, role = wave & 1;
  const int m    = lane & 31, hl = lane >> 5;
  const int R0   = blockIdx.x*128 + pair*32;   // pair's 32 batch rows
  u16* hw = hn[pair];
  const int scol = role*192;                   // role's scratch col base

  const float gt   = gate[R0 + m];
  const float bd1v = bd1[role*32 + m];
  const float bd2v = (m<3) ? bd2[m] : 0.f;

  if (role==0 && lane < 32){
    const float* sp = istate + (size_t)(R0+lane)*3;
    sst[pair][lane][0]=sp[0]; sst[pair][lane][1]=sp[1];
    sst[pair][lane][2]=sp[2]; sst[pair][lane][3]=0.f;
  }

  // initial hidden -> A-frags (both roles); role 0 seeds the LDS h-buffer
  u16x8 hold[24];
#pragma unroll
  for (int kf=0; kf<24; ++kf){
    const float* p = ih + (size_t)(R0+m)*384 + kf*16 + hl*8;
    float4 a = *(const float4*)p;
    float4 b = *(const float4*)(p+4);
    u16x8 v;
    v[0]=f2b(a.x); v[1]=f2b(a.y); v[2]=f2b(a.z); v[3]=f2b(a.w);
    v[4]=f2b(b.x); v[5]=f2b(b.y); v[6]=f2b(b.z); v[7]=f2b(b.w);
    hold[kf]=v;
    if (role==0) *(u16x8*)&hw[m*HS + kf*16 + hl*8] = v;
  }

  const u16* srcb = stream + wave*1536 + lane*8;  // 8 waves x 1536 u16 stripes
  auto stage = [&](int sp, int bsel){
    const u16* s = srcb + (size_t)sp*SPU;
    u16* d = &wb[bsel][wave*1536];
#pragma unroll
    for (int ii=0; ii<3; ++ii) stage16(s + ii*512, d + ii*512);
  };

  stage(0, 0);
  vm_fence(); __syncthreads();
  int buf = 0, gp = 0;

#pragma unroll 1
  for (int t=0; t<TT; ++t){
    // ---- x = (state@Ws^T+bs) + gate*(plan@Wp^T+bp); both roles build full xf
    u16x8 a8;
    {
      float4 sv = *(const float4*)&sst[pair][m][0];
      const float* pp = plan + (size_t)(R0+m)*(TT*3) + t*3;
      float f0=sv.x, f1=sv.y, f2=sv.z, f3=1.f;
      float f4=gt*pp[0], f5=gt*pp[1], f6=gt*pp[2], f7=gt;
      if (hl){ a8[0]=0;a8[1]=0;a8[2]=0;a8[3]=0;a8[4]=0;a8[5]=0;a8[6]=0;a8[7]=0; }
      else { a8[0]=f2b(f0);a8[1]=f2b(f1);a8[2]=f2b(f2);a8[3]=f2b(f3);
             a8[4]=f2b(f4);a8[5]=f2b(f5);a8[6]=f2b(f6);a8[7]=f2b(f7); }
    }
    u16x8 xf[8];
#pragma unroll
    for (int tl=0; tl<4; ++tl){
      f32x16 ax;
#pragma unroll
      for (int r=0;r<16;++r) ax[r]=0.f;
      ax = mfma32(a8, *(const u16x8*)(wxp + tl*512 + lane*8), ax);
      // C-layout -> own scratch slice -> A-frags
#pragma unroll
      for (int r=0;r<16;++r){
        int row = (r&3) + ((r>>2)<<3) + 4*hl;
        hw[row*HS + scol + m] = f2b(ax[r]);
      }
      lds_fence();
      xf[2*tl]   = *(const u16x8*)&hw[m*HS + scol + hl*8];
      xf[2*tl+1] = *(const u16x8*)&hw[m*HS + scol + 16 + hl*8];
      lds_fence();
    }
    // restore own slice with old h (CONSTANT reg indices via role branch)
    if (role==0){
      *(u16x8*)&hw[m*HS + hl*8]       = hold[0];
      *(u16x8*)&hw[m*HS + 16 + hl*8]  = hold[1];
    } else {
      *(u16x8*)&hw[m*HS + 192 + hl*8] = hold[12];
      *(u16x8*)&hw[m*HS + 208 + hl*8] = hold[13];
    }
    lds_fence();

    // ---- 6 chunks x 8 superphases (role's chunks: role*6 + ci)
#pragma unroll 1
    for (int ci=0; ci<6; ++ci){
      const int colb = scol + ci*32;           // this chunk's h columns
      f32x16 aR, aZ, aNI, aNH;
      {
        const float4 b4 = *(const float4*)(gb + (size_t)(colb+m)*4);
#pragma unroll
        for (int r=0;r<16;++r){ aR[r]=b4.x; aZ[r]=b4.y; aNI[r]=b4.z; aNH[r]=b4.w; }
      }
      { // hp0: gi_r kf0..7 (f0..7), gi_z kf0..3 (f8..11)
        int np = gp+1; stage(np, buf^1);
        const u16* W = wb[buf] + role*RHU;
#pragma unroll
        for (int kf=0; kf<8; ++kf)
          aR = mfma32(xf[kf], *(const u16x8*)(W + kf*512 + lane*8), aR);
#pragma unroll
        for (int kf=0; kf<4; ++kf)
          aZ = mfma32(xf[kf], *(const u16x8*)(W + (8+kf)*512 + lane*8), aZ);
        vm_fence(); __syncthreads(); buf^=1; gp=np;
      }
      { // hp1: gi_z kf4..7 (f0..3), gi_n kf0..7 (f4..11)
        int np = gp+1; stage(np, buf^1);
        const u16* W = wb[buf] + role*RHU;
#pragma unroll
        for (int kf=4; kf<8; ++kf)
          aZ = mfma32(xf[kf], *(const u16x8*)(W + (kf-4)*512 + lane*8), aZ);
#pragma unroll
        for (int kf=0; kf<8; ++kf)
          aNI = mfma32(xf[kf], *(const u16x8*)(W + (4+kf)*512 + lane*8), aNI);
        vm_fence(); __syncthreads(); buf^=1; gp=np;
      }
      { // hp2: gh_r kf0..11
        int np = gp+1; stage(np, buf^1);
        const u16* W = wb[buf] + role*RHU;
#pragma unroll
        for (int kf=0; kf<12; ++kf)
          aR = mfma32(hold[kf], *(const u16x8*)(W + kf*512 + lane*8), aR);
        vm_fence(); __syncthreads(); buf^=1; gp=np;
      }
      { // hp3: gh_r kf12..23
        int np = gp+1; stage(np, buf^1);
        const u16* W = wb[buf] + role*RHU;
#pragma unroll
        for (int kk=0; kk<12; ++kk)
          aR = mfma32(hold[12+kk], *(const u16x8*)(W + kk*512 + lane*8), aR);
        vm_fence(); __syncthreads(); buf^=1; gp=np;
      }
      { // hp4: gh_z kf0..11
        int np = gp+1; stage(np, buf^1);
        const u16* W = wb[buf] + role*RHU;
#pragma unroll
        for (int kf=0; kf<12; ++kf)
          aZ = mfma32(hold[kf], *(const u16x8*)(W + kf*512 + lane*8), aZ);
        vm_fence(); __syncthreads(); buf^=1; gp=np;
      }
      { // hp5: gh_z kf12..23
        int np = gp+1; stage(np, buf^1);
        const u16* W = wb[buf] + role*RHU;
#pragma unroll
        for (int kk=0; kk<12; ++kk)
          aZ = mfma32(hold[12+kk], *(const u16x8*)(W + kk*512 + lane*8), aZ);
        vm_fence(); __syncthreads(); buf^=1; gp=np;
      }
      { // hp6: gh_n kf0..11
        int np = gp+1; stage(np, buf^1);
        const u16* W = wb[buf] + role*RHU;
#pragma unroll
        for (int kf=0; kf<12; ++kf)
          aNH = mfma32(hold[kf], *(const u16x8*)(W + kf*512 + lane*8), aNH);
        vm_fence(); __syncthreads(); buf^=1; gp=np;
      }
      { // hp7: gh_n kf12..23 + GRU elementwise blend in place
        int np = gp+1; stage(np, buf^1);
        const u16* W = wb[buf] + role*RHU;
#pragma unroll
        for (int kk=0; kk<12; ++kk)
          aNH = mfma32(hold[12+kk], *(const u16x8*)(W + kk*512 + lane*8), aNH);
#pragma unroll
        for (int r=0;r<16;++r){
          int row = (r&3) + ((r>>2)<<3) + 4*hl;
          float rr = sigf(aR[r]);
          float zz = sigf(aZ[r]);
          float nn = tanh_(aNI[r] + rr*aNH[r]);
          int off = row*HS + colb + m;
          float ho = b2f(hw[off]);             // old h
          hw[off] = f2b((1.f-zz)*nn + zz*ho);  // new h, in place
        }
        vm_fence(); __syncthreads(); buf^=1; gp=np;
      }
    } // chunks

    // ---- reload hold[] (full new h; all blends done before hp47's barrier)
#pragma unroll
    for (int kf=0; kf<24; ++kf)
      hold[kf] = *(const u16x8*)&hw[m*HS + kf*16 + hl*8];

    // ---- decode: this role's Wd1 tile over 2 superphases
    f32x16 a0;
#pragma unroll
    for (int r=0;r<16;++r) a0[r]=bd1v;
    { // hp48: Wd1 tile kf0..11
      int np = gp+1; stage(np, buf^1);
      const u16* W = wb[buf] + role*RHU;
#pragma unroll
      for (int kf=0; kf<12; ++kf)
        a0 = mfma32(hold[kf], *(const u16x8*)(W + kf*512 + lane*8), a0);
      vm_fence(); __syncthreads(); buf^=1; gp=np;
    }
    { // hp49: Wd1 tile kf12..23 + elu into own scratch slice; stage wraps
      int np = (gp+1 == NHP) ? 0 : gp+1;
      stage(np, buf^1);
      const u16* W = wb[buf] + role*RHU;
#pragma unroll
      for (int kk=0; kk<12; ++kk)
        a0 = mfma32(hold[12+kk], *(const u16x8*)(W + kk*512 + lane*8), a0);
#pragma unroll
      for (int r=0;r<16;++r){
        int row = (r&3) + ((r>>2)<<3) + 4*hl;
        float e = a0[r]; e = e>0.f ? e : (__expf(e)-1.f);
        hw[row*HS + scol + m] = f2b(e);
      }
      vm_fence(); __syncthreads(); buf^=1; gp=np;
    }
    // ---- epilogue: d2 from BOTH roles' elu slices
    {
      u16x8 wd2f0 = *(const u16x8*)(wd2p + 0*512 + lane*8);
      u16x8 wd2f1 = *(const u16x8*)(wd2p + 1*512 + lane*8);
      u16x8 wd2f2 = *(const u16x8*)(wd2p + 2*512 + lane*8);
      u16x8 wd2f3 = *(const u16x8*)(wd2p + 3*512 + lane*8);

      u16x8 af0 = *(const u16x8*)&hw[m*HS + hl*8];         // d1 units  0..15
      u16x8 af1 = *(const u16x8*)&hw[m*HS + 16  + hl*8];   //          16..31
      u16x8 af2 = *(const u16x8*)&hw[m*HS + 192 + hl*8];   //          32..47
      u16x8 af3 = *(const u16x8*)&hw[m*HS + 208 + hl*8];   //          48..63
      f32x16 ao;
#pragma unroll
      for (int r=0;r<16;++r) ao[r]=0.f;
      ao = mfma32(af0, wd2f0, ao);
      ao = mfma32(af1, wd2f1, ao);
      ao = mfma32(af2, wd2f2, ao);
      ao = mfma32(af3, wd2f3, ao);

      // all cross-slice reads done before anyone overwrites the slices
      __syncthreads();

      // restore own slice with NEW h (constant reg indices via role branch)
      if (role==0){
        *(u16x8*)&hw[m*HS + hl*8]       = hold[0];
        *(u16x8*)&hw[m*HS + 16 + hl*8]  = hold[1];
      } else {
        *(u16x8*)&hw[m*HS + 192 + hl*8] = hold[12];
        *(u16x8*)&hw[m*HS + 208 + hl*8] = hold[13];
      }

      // out + state update (role 0 writes; C cols 0..2 valid)
      if (role==0){
#pragma unroll
        for (int r=0;r<16;++r){
          int row = (r&3) + ((r>>2)<<3) + 4*hl;
          if (m < 3){
            float ns = sst[pair][row][m] + ao[r] + bd2v;
            out[(size_t)(R0+row)*(TT*3) + t*3 + m] = ns;
            sst[pair][row][m] = ns;
          }
        }
      }
      __syncthreads();   // sst + slice restores visible before next t
    }
  } // t
}

// -------------------------------------------------------------- launch ----
extern "C" void kernel_launch(void* const* d_in, const int* in_sizes, int n_in,
                              void* d_out, int out_size, void* d_ws, size_t ws_size,
                              hipStream_t stream)
{
  (void)in_sizes; (void)n_in; (void)out_size; (void)ws_size;
  const float* ih     = (const float*)d_in[0];
  const float* plan   = (const float*)d_in[1];
  const float* gatep  = (const float*)d_in[2];
  const float* istate = (const float*)d_in[3];
  const float* Wp     = (const float*)d_in[4];
  const float* bp     = (const float*)d_in[5];
  const float* Ws     = (const float*)d_in[6];
  const float* bs     = (const float*)d_in[7];
  const float* Wih    = (const float*)d_in[8];
  const float* bih    = (const float*)d_in[9];
  const float* Whh    = (const float*)d_in[10];
  const float* bhh    = (const float*)d_in[11];
  const float* Wd1    = (const float*)d_in[12];
  const float* bd1    = (const float*)d_in[13];
  const float* Wd2    = (const float*)d_in[14];
  const float* bd2    = (const float*)d_in[15];

  // workspace layout (~1.25 MB)
  u16*   wstream = (u16*)d_ws;                         // 614400 u16 = 1228800 B
  u16*   wd2p    = (u16*)((char*)d_ws + 1228800);      //   2048 u16 =    4096 B
  u16*   wxp     = (u16*)((char*)d_ws + 1232896);      //   2048 u16 =    4096 B
  float* gb      = (float*)((char*)d_ws + 1236992);    //   1536 f32 =    6144 B

  prep_kernel<<<1728, 256, 0, stream>>>(Wih, Whh, Wd1, Wd2, bih, bhh, Ws, bs, Wp, bp,
                                        wstream, wd2p, wxp, gb);
  gru_main<<<256, 512, 0, stream>>>(ih, plan, gatep, istate,
                                    wstream, wd2p, wxp, gb, bd1, bd2, (float*)d_out);
}

// Round 7
// 1718.823 us; speedup vs baseline: 1.1366x; 1.1358x over previous
//
#include <hip/hip_runtime.h>

// Decoder_8014408974552 R11: resubmission of R10 (counted-vmcnt 5-slot
// pipeline) after an infra-level container failure (no timing block at all
// -> never ran). Audit found no deadlock path: uniform barriers, in-order
// vmcnt retirement (extra compiler loads only STRENGTHEN the counted wait),
// slot schedule race-free incl. t-boundary wrap, all offsets in bounds.
// Hardening added per guide rule #18: sched_barrier(0) after every
// inline-asm s_waitcnt so hipcc cannot hoist dependent ops above it.
// Structure: R4 base; wb = 5 x 12KB half-phase slots; phase p stages halves
// 2p+3,2p+4 and reads 2p,2p+1; phase end = s_waitcnt vmcnt(3) lgkmcnt(0) +
// raw s_barrier (NEVER vmcnt(0) -- the __syncthreads drain was the target).
// sst folded into hn row padding; LDS 161792 B. prep/stream layout = R4.

#define TT  30
#define NPH 50
#define PHU 12288   // u16 per phase (24576 B) -- prep layout unit
#define HPU 6144    // u16 per half-phase slot (12288 B)
#define STRU 614400 // u16 in the whole stream (100 halves)
#define HS  392     // hn row stride in u16 (784 B; cols 384..391 = sst)

typedef unsigned short u16;
typedef __bf16 bf16x8 __attribute__((ext_vector_type(8)));
typedef u16    u16x8  __attribute__((ext_vector_type(8)));
typedef float  f32x16 __attribute__((ext_vector_type(16)));

__device__ __forceinline__ u16 f2b(float f){           // fp32 -> bf16 RNE
  unsigned u = __float_as_uint(f);
  u += 0x7FFFu + ((u >> 16) & 1u);
  return (u16)(u >> 16);
}
__device__ __forceinline__ float b2f(u16 h){ return __uint_as_float(((unsigned)h) << 16); }

__device__ __forceinline__ f32x16 mfma32(u16x8 a, u16x8 b, f32x16 c){
  return __builtin_amdgcn_mfma_f32_32x32x16_bf16(
      __builtin_bit_cast(bf16x8, a), __builtin_bit_cast(bf16x8, b), c, 0, 0, 0);
}
__device__ __forceinline__ void lds_fence(){
  asm volatile("s_waitcnt lgkmcnt(0)" ::: "memory");
  __builtin_amdgcn_sched_barrier(0);
}
__device__ __forceinline__ float sigf(float x){ return __builtin_amdgcn_rcpf(1.f + __expf(-x)); }
__device__ __forceinline__ float tanh_(float x){ return 2.f*__builtin_amdgcn_rcpf(1.f + __expf(-2.f*x)) - 1.f; }

__device__ __forceinline__ void stage16(const u16* g, u16* l){
  __builtin_amdgcn_global_load_lds(
      (const __attribute__((address_space(1))) unsigned int*)g,
      (__attribute__((address_space(3))) unsigned int*)l, 16, 0, 0);
}

// ---------------------------------------------------------------- prep ----
// EXACT R4 layout (50 phases x 24 frags x 1024 B per step):
//   c*4+0 : gi  [gi_r kf0..7][gi_z kf0..7][gi_n kf0..7]   (K=128)
//   c*4+1 : gh_r kf0..23   c*4+2 : gh_z   c*4+3 : gh_n     (K=384)
//   48,49 : Wd1 col-tile 0,1  kf0..23
// frag: u16 idx (lane&31 + 32*(lane>>5))*8 + j -> B[k][n], n=c*32+(lane&31),
// k = kf*16 + (lane>>5)*8 + j.  (Half-phase h = 2p + f/12 at h*HPU.)
__global__ void prep_kernel(const float* __restrict__ Wih, const float* __restrict__ Whh,
                            const float* __restrict__ Wd1, const float* __restrict__ Wd2,
                            const float* __restrict__ bih, const float* __restrict__ bhh,
                            const float* __restrict__ Ws,  const float* __restrict__ bs,
                            const float* __restrict__ Wp,  const float* __restrict__ bp,
                            u16* __restrict__ stream, u16* __restrict__ wd2p,
                            u16* __restrict__ wxp, float* __restrict__ gb)
{
  int i = blockIdx.x*blockDim.x + threadIdx.x;
  if (i < 442368){  // W_hh [1152][384]
    int row = i/384, k = i - row*384;
    int g = row/384, unit = row - g*384, c = unit>>5, lc = unit&31;
    int kf = k>>4, hl = (k>>3)&1, j = k&7;
    int phase = c*4 + 1 + g;
    stream[(size_t)phase*PHU + kf*512 + (lc+32*hl)*8 + j] = f2b(Whh[i]);
  }
  if (i < 147456){  // W_ih [1152][128]
    int row = i>>7, k = i&127;
    int g = row/384, unit = row - g*384, c = unit>>5, lc = unit&31;
    int kf = k>>4, hl = (k>>3)&1, j = k&7;
    int phase = c*4;
    stream[(size_t)phase*PHU + (g*8+kf)*512 + (lc+32*hl)*8 + j] = f2b(Wih[i]);
  }
  if (i < 24576){   // Wd1 [64][384]
    int row = i/384, k = i - row*384;
    int ct = row>>5, lc = row&31;
    int kf = k>>4, hl = (k>>3)&1, j = k&7;
    int phase = 48 + ct;
    stream[(size_t)phase*PHU + kf*512 + (lc+32*hl)*8 + j] = f2b(Wd1[i]);
  }
  if (i < 2048){    // Wd2 padded B-frags [4 kf][512] (n>=3 -> 0)
    int kf = i>>9, r = i&511;
    int n = (r>>3)&31, hl = r>>8, j = r&7;
    int k = kf*16 + hl*8 + j;
    wd2p[i] = f2b((n<3) ? Wd2[n*64 + k] : 0.f);
  }
  if (i < 2048){    // x-MLP B-frags [4 tiles][512]: K=16 (k=0..7 feat, 8..15 zero)
    int tl = i>>9, r = i&511;
    int n = (r>>3)&31, hl = r>>8, j = r&7;
    int k = hl*8 + j, u = tl*32 + n;
    float v = 0.f;
    if      (k <= 2) v = Ws[u*3 + k];
    else if (k == 3) v = bs[u];
    else if (k <= 6) v = Wp[u*3 + (k-4)];
    else if (k == 7) v = bp[u];
    wxp[i] = f2b(v);
  }
  if (i < 384){     // fused gate biases per hidden unit: {r, z, n_i, n_h}
    gb[i*4+0] = bih[i]       + bhh[i];
    gb[i*4+1] = bih[384+i]   + bhh[384+i];
    gb[i*4+2] = bih[768+i];
    gb[i*4+3] = bhh[768+i];
  }
}

// ---------------------------------------------------------------- main ----
__global__ __launch_bounds__(256, 1)
void gru_main(const float* __restrict__ ih, const float* __restrict__ plan,
              const float* __restrict__ gate, const float* __restrict__ istate,
              const u16* __restrict__ stream, const u16* __restrict__ wd2p,
              const u16* __restrict__ wxp, const float* __restrict__ gb,
              const float* __restrict__ bd1, const float* __restrict__ bd2,
              float* __restrict__ out)
{
  __shared__ __attribute__((aligned(16))) u16 wb[5*HPU];    //  61440 B, 5 half-slots
  __shared__ __attribute__((aligned(16))) u16 hn[4][32*HS]; // 100352 B (h + sst pad)
  // total 161792 B <= 163840

  const int tid  = threadIdx.x;
  const int wave = tid >> 6, lane = tid & 63;
  const int m    = lane & 31, hl = lane >> 5;
  const int R0   = blockIdx.x*128 + wave*32;   // wave's 32 batch rows
  u16* hw = hn[wave];

  const float gt    = gate[R0 + m];
  const float bd1v0 = bd1[m], bd1v1 = bd1[32+m];
  const float bd2v  = (m<3) ? bd2[m] : 0.f;

  if (lane < 32){   // sst lives in hn row padding (cols 384..391 = 4 f32)
    const float* sp = istate + (size_t)(R0+lane)*3;
    float* q = (float*)&hw[lane*HS + 384];
    q[0]=sp[0]; q[1]=sp[1]; q[2]=sp[2]; q[3]=0.f;
  }

  // initial hidden -> A-frags AND the persistent LDS h-buffer
  u16x8 hold[24];
#pragma unroll
  for (int kf=0; kf<24; ++kf){
    const float* p = ih + (size_t)(R0+m)*384 + kf*16 + hl*8;
    float4 a = *(const float4*)p;
    float4 b = *(const float4*)(p+4);
    u16x8 v;
    v[0]=f2b(a.x); v[1]=f2b(a.y); v[2]=f2b(a.z); v[3]=f2b(a.w);
    v[4]=f2b(b.x); v[5]=f2b(b.y); v[6]=f2b(b.z); v[7]=f2b(b.w);
    hold[kf]=v;
    *(u16x8*)&hw[m*HS + kf*16 + hl*8] = v;
  }

  // ---- counted-vmcnt staging pipeline state ----
  int hoff = 0;            // stream u16 offset of next half to stage (wraps)
  int ss   = 0;            // its slot (= half index mod 5)
  int sa   = 0, sb = 1;    // slots read by the current phase
  auto stage_half = [&](){ // one 12KB half: 3 stage16 per wave
    const u16* s = stream + hoff + wave*1536 + lane*8;
    u16* d = &wb[ss*HPU + wave*1536];
    stage16(s,        d);
    stage16(s + 512,  d + 512);
    stage16(s + 1024, d + 1024);
    hoff += HPU; if (hoff == STRU) hoff = 0;
    ss = (ss==4) ? 0 : ss+1;
  };
  auto phase_end = [&](){  // counted wait: leave the newest half in flight
    asm volatile("s_waitcnt vmcnt(3) lgkmcnt(0)" ::: "memory");
    __builtin_amdgcn_sched_barrier(0);
    __builtin_amdgcn_s_barrier();
    __builtin_amdgcn_sched_barrier(0);
    sa = (sa>=3) ? sa-3 : sa+2;
    sb = (sb>=3) ? sb-3 : sb+2;
  };

  // prologue: halves 0,1 landed; half 2 in flight
  stage_half(); stage_half(); stage_half();
  asm volatile("s_waitcnt vmcnt(3) lgkmcnt(0)" ::: "memory");
  __builtin_amdgcn_sched_barrier(0);
  __builtin_amdgcn_s_barrier();
  __builtin_amdgcn_sched_barrier(0);

#pragma unroll 1
  for (int t=0; t<TT; ++t){
    // ---- x = (state@Ws^T+bs) + gate*(plan@Wp^T+bp) via one padded-K MFMA per tile
    u16x8 a8;
    {
      float4 sv = *(const float4*)&hw[m*HS + 384];   // sst in hn padding
      const float* pp = plan + (size_t)(R0+m)*(TT*3) + t*3;
      float f0=sv.x, f1=sv.y, f2=sv.z, f3=1.f;
      float f4=gt*pp[0], f5=gt*pp[1], f6=gt*pp[2], f7=gt;
      if (hl){ a8[0]=0;a8[1]=0;a8[2]=0;a8[3]=0;a8[4]=0;a8[5]=0;a8[6]=0;a8[7]=0; }
      else { a8[0]=f2b(f0);a8[1]=f2b(f1);a8[2]=f2b(f2);a8[3]=f2b(f3);
             a8[4]=f2b(f4);a8[5]=f2b(f5);a8[6]=f2b(f6);a8[7]=f2b(f7); }
    }
    u16x8 xf[8];
#pragma unroll
    for (int tl=0; tl<4; ++tl){
      f32x16 ax;
#pragma unroll
      for (int r=0;r<16;++r) ax[r]=0.f;
      ax = mfma32(a8, *(const u16x8*)(wxp + tl*512 + lane*8), ax);
      // C-layout -> hn chunk-0 slice (scratch) -> A-frags
#pragma unroll
      for (int r=0;r<16;++r){
        int row = (r&3) + ((r>>2)<<3) + 4*hl;
        hw[row*HS + m] = f2b(ax[r]);
      }
      lds_fence();
      xf[2*tl]   = *(const u16x8*)&hw[m*HS + hl*8];
      xf[2*tl+1] = *(const u16x8*)&hw[m*HS + 16 + hl*8];
      lds_fence();
    }
    // restore chunk-0 slice of old h from hold (CONSTANT indices)
    *(u16x8*)&hw[m*HS + hl*8]      = hold[0];
    *(u16x8*)&hw[m*HS + 16 + hl*8] = hold[1];
    lds_fence();

#pragma unroll 1
    for (int c=0; c<12; ++c){
      f32x16 aR, aZ, aNI, aNH;
      {
        const float4 b4 = *(const float4*)(gb + (size_t)(c*32+m)*4);
#pragma unroll
        for (int r=0;r<16;++r){ aR[r]=b4.x; aZ[r]=b4.y; aNI[r]=b4.z; aNH[r]=b4.w; }
      }
      { // phase c*4: gi (frags 0..23 across slots sa|sb)
        stage_half(); stage_half();
        const u16* W0 = wb + sa*HPU;
        const u16* W1 = wb + sb*HPU;
#pragma unroll
        for (int kf=0; kf<8; ++kf){
          const u16* bR = W0 + kf*512;                                   // frag kf
          const u16* bZ = (kf<4) ? W0 + (8+kf)*512 : W1 + (kf-4)*512;    // frag 8+kf
          const u16* bN = W1 + (4+kf)*512;                               // frag 16+kf
          aR  = mfma32(xf[kf], *(const u16x8*)(bR + lane*8), aR);
          aZ  = mfma32(xf[kf], *(const u16x8*)(bZ + lane*8), aZ);
          aNI = mfma32(xf[kf], *(const u16x8*)(bN + lane*8), aNI);
        }
        phase_end();
      }
      { // phase c*4+1: gh_r
        stage_half(); stage_half();
        const u16* W0 = wb + sa*HPU;
        const u16* W1 = wb + sb*HPU;
#pragma unroll
        for (int kf=0; kf<24; ++kf){
          const u16* Bp = (kf<12) ? W0 + kf*512 : W1 + (kf-12)*512;
          aR = mfma32(hold[kf], *(const u16x8*)(Bp + lane*8), aR);
        }
        phase_end();
      }
      { // phase c*4+2: gh_z
        stage_half(); stage_half();
        const u16* W0 = wb + sa*HPU;
        const u16* W1 = wb + sb*HPU;
#pragma unroll
        for (int kf=0; kf<24; ++kf){
          const u16* Bp = (kf<12) ? W0 + kf*512 : W1 + (kf-12)*512;
          aZ = mfma32(hold[kf], *(const u16x8*)(Bp + lane*8), aZ);
        }
        phase_end();
      }
      { // phase c*4+3: gh_n + GRU elementwise, blended in place in hn slice
        stage_half(); stage_half();
        const u16* W0 = wb + sa*HPU;
        const u16* W1 = wb + sb*HPU;
#pragma unroll
        for (int kf=0; kf<24; ++kf){
          const u16* Bp = (kf<12) ? W0 + kf*512 : W1 + (kf-12)*512;
          aNH = mfma32(hold[kf], *(const u16x8*)(Bp + lane*8), aNH);
        }
#pragma unroll
        for (int r=0;r<16;++r){
          int row = (r&3) + ((r>>2)<<3) + 4*hl;
          float rr = sigf(aR[r]);
          float zz = sigf(aZ[r]);
          float nn = tanh_(aNI[r] + rr*aNH[r]);
          int off = row*HS + c*32 + m;
          float ho = b2f(hw[off]);             // old h
          hw[off] = f2b((1.f-zz)*nn + zz*ho);  // new h, in place
        }
        phase_end();
      }
    } // chunks

    // ---- reload hold[] from hn (full new h for this wave's 32 rows)
    lds_fence();
#pragma unroll
    for (int kf=0; kf<24; ++kf)
      hold[kf] = *(const u16x8*)&hw[m*HS + kf*16 + hl*8];

    // ---- decode: d1 = elu(h@Wd1^T + bd1) [2 tiles], then d2 via padded-N MFMA
    f32x16 a0, a1;
#pragma unroll
    for (int r=0;r<16;++r){ a0[r]=bd1v0; a1[r]=bd1v1; }
    { // phase 48: Wd1 tile 0
      stage_half(); stage_half();
      const u16* W0 = wb + sa*HPU;
      const u16* W1 = wb + sb*HPU;
#pragma unroll
      for (int kf=0; kf<24; ++kf){
        const u16* Bp = (kf<12) ? W0 + kf*512 : W1 + (kf-12)*512;
        a0 = mfma32(hold[kf], *(const u16x8*)(Bp + lane*8), a0);
      }
      phase_end();
    }
    { // phase 49: Wd1 tile 1 (+ epilogue); staging wraps into next t's stream
      stage_half(); stage_half();
      const u16* W0 = wb + sa*HPU;
      const u16* W1 = wb + sb*HPU;
#pragma unroll
      for (int kf=0; kf<24; ++kf){
        const u16* Bp = (kf<12) ? W0 + kf*512 : W1 + (kf-12)*512;
        a1 = mfma32(hold[kf], *(const u16x8*)(Bp + lane*8), a1);
      }

      // Wd2 frags (short live range, L1-hot)
      u16x8 wd2f0 = *(const u16x8*)(wd2p + 0*512 + lane*8);
      u16x8 wd2f1 = *(const u16x8*)(wd2p + 1*512 + lane*8);
      u16x8 wd2f2 = *(const u16x8*)(wd2p + 2*512 + lane*8);
      u16x8 wd2f3 = *(const u16x8*)(wd2p + 3*512 + lane*8);

      f32x16 ao;
#pragma unroll
      for (int r=0;r<16;++r) ao[r]=0.f;
      // pass 0: d1 units 0..31 (hn chunk-0 slice as scratch)
#pragma unroll
      for (int r=0;r<16;++r){
        int row = (r&3) + ((r>>2)<<3) + 4*hl;
        float e = a0[r]; e = e>0.f ? e : (__expf(e)-1.f);
        hw[row*HS + m] = f2b(e);
      }
      lds_fence();
      {
        u16x8 af0 = *(const u16x8*)&hw[m*HS + hl*8];
        u16x8 af1 = *(const u16x8*)&hw[m*HS + 16 + hl*8];
        ao = mfma32(af0, wd2f0, ao);
        ao = mfma32(af1, wd2f1, ao);
      }
      lds_fence();
      // pass 1: d1 units 32..63
#pragma unroll
      for (int r=0;r<16;++r){
        int row = (r&3) + ((r>>2)<<3) + 4*hl;
        float e = a1[r]; e = e>0.f ? e : (__expf(e)-1.f);
        hw[row*HS + m] = f2b(e);
      }
      lds_fence();
      {
        u16x8 af0 = *(const u16x8*)&hw[m*HS + hl*8];
        u16x8 af1 = *(const u16x8*)&hw[m*HS + 16 + hl*8];
        ao = mfma32(af0, wd2f2, ao);
        ao = mfma32(af1, wd2f3, ao);
      }
      lds_fence();
      // restore chunk-0 slice of NEW h from hold (CONSTANT indices)
      *(u16x8*)&hw[m*HS + hl*8]      = hold[0];
      *(u16x8*)&hw[m*HS + 16 + hl*8] = hold[1];

      // out + state update (C cols 0..2 valid); sst in hn padding
#pragma unroll
      for (int r=0;r<16;++r){
        int row = (r&3) + ((r>>2)<<3) + 4*hl;
        if (m < 3){
          float* q = (float*)&hw[row*HS + 384];
          float ns = q[m] + ao[r] + bd2v;
          out[(size_t)(R0+row)*(TT*3) + t*3 + m] = ns;
          q[m] = ns;
        }
      }
      phase_end();
    }
  } // t
}

// -------------------------------------------------------------- launch ----
extern "C" void kernel_launch(void* const* d_in, const int* in_sizes, int n_in,
                              void* d_out, int out_size, void* d_ws, size_t ws_size,
                              hipStream_t stream)
{
  (void)in_sizes; (void)n_in; (void)out_size; (void)ws_size;
  const float* ih     = (const float*)d_in[0];
  const float* plan   = (const float*)d_in[1];
  const float* gatep  = (const float*)d_in[2];
  const float* istate = (const float*)d_in[3];
  const float* Wp     = (const float*)d_in[4];
  const float* bp     = (const float*)d_in[5];
  const float* Ws     = (const float*)d_in[6];
  const float* bs     = (const float*)d_in[7];
  const float* Wih    = (const float*)d_in[8];
  const float* bih    = (const float*)d_in[9];
  const float* Whh    = (const float*)d_in[10];
  const float* bhh    = (const float*)d_in[11];
  const float* Wd1    = (const float*)d_in[12];
  const float* bd1    = (const float*)d_in[13];
  const float* Wd2    = (const float*)d_in[14];
  const float* bd2    = (const float*)d_in[15];

  // workspace layout (~1.25 MB)
  u16*   wstream = (u16*)d_ws;                         // 614400 u16 = 1228800 B
  u16*   wd2p    = (u16*)((char*)d_ws + 1228800);      //   2048 u16 =    4096 B
  u16*   wxp     = (u16*)((char*)d_ws + 1232896);      //   2048 u16 =    4096 B
  float* gb      = (float*)((char*)d_ws + 1236992);    //   1536 f32 =    6144 B

  prep_kernel<<<1728, 256, 0, stream>>>(Wih, Whh, Wd1, Wd2, bih, bhh, Ws, bs, Wp, bp,
                                        wstream, wd2p, wxp, gb);
  gru_main<<<256, 256, 0, stream>>>(ih, plan, gatep, istate,
                                    wstream, wd2p, wxp, gb, bd1, bd2, (float*)d_out);
}